// Round 16
// baseline (366.554 us; speedup 1.0000x reference)
//
#include <hip/hip_runtime.h>
#include <math.h>

static constexpr int Bc = 32;
static constexpr int Lc = 1024;

typedef _Float16 f16x4 __attribute__((ext_vector_type(4)));
typedef __fp16   h16x2 __attribute__((ext_vector_type(2)));   // cvt_pkrtz result type
typedef float    f32x4 __attribute__((ext_vector_type(4)));

#define MFMA16(a, b, c) __builtin_amdgcn_mfma_f32_16x16x16f16((a), (b), (c), 0, 0, 0)

#if __has_builtin(__builtin_amdgcn_exp2f)
#define EXP2(x) __builtin_amdgcn_exp2f(x)
#else
#define EXP2(x) exp2f(x)
#endif

__device__ inline float fdot2_acc(h16x2 a, float c) {
#if __has_builtin(__builtin_amdgcn_fdot2)
    h16x2 one2 = { (__fp16)1.f, (__fp16)1.f };
    return __builtin_amdgcn_fdot2(a, one2, c, false);
#else
    return c + (float)a[0] + (float)a[1];
#endif
}

// ---------------------------------------------------------------------------
// Fused prep: features f32->f16, rel f32->f16, weight transpose+convert.
// ---------------------------------------------------------------------------
__global__ __launch_bounds__(256) void prep_kernel(
    const float* __restrict__ features, const float* __restrict__ rel,
    const float* __restrict__ Wq, const float* __restrict__ Wk,
    const float* __restrict__ Wv, const float* __restrict__ Wo,
    const float* __restrict__ Wi, const float* __restrict__ Wd,
    _Float16* __restrict__ xh, _Float16* __restrict__ relh,
    _Float16* __restrict__ wt)
{
    int i = blockIdx.x * 256 + threadIdx.x;          // 0..524287
    {
        float4 v = ((const float4*)features)[i];
        h16x2 a = __builtin_amdgcn_cvt_pkrtz(v.x, v.y);
        h16x2 b = __builtin_amdgcn_cvt_pkrtz(v.z, v.w);
        f16x4 o; o[0] = a[0]; o[1] = a[1]; o[2] = b[0]; o[3] = b[1];
        ((f16x4*)xh)[i] = o;
    }
    if (i < 32752) {
        float4 v = ((const float4*)rel)[i];
        h16x2 a = __builtin_amdgcn_cvt_pkrtz(v.x, v.y);
        h16x2 b = __builtin_amdgcn_cvt_pkrtz(v.z, v.w);
        f16x4 o; o[0] = a[0]; o[1] = a[1]; o[2] = b[0]; o[3] = b[1];
        ((f16x4*)relh)[i] = o;
    }
    if (i < 65536) {
        int which = i >> 14, r = i & 16383;
        int m = r >> 12, k = (r >> 6) & 63, c = r & 63;
        const float* src = which == 0 ? Wq : which == 1 ? Wk : which == 2 ? Wv : Wo;
        wt[which * 16384 + m * 4096 + c * 64 + k] = (_Float16)src[r];
    } else if (i < 73728) {
        int r = i - 65536;                    // Wi [4][64][32]
        int m = r >> 11, k = (r >> 5) & 63, c = r & 31;
        wt[65536 + m * 2048 + c * 64 + k] = (_Float16)Wi[r];
    } else if (i < 81920) {
        int r = i - 73728;                    // Wd [4][32][64]
        int m = r >> 11, k = (r >> 6) & 31, c = r & 63;
        wt[73728 + m * 2048 + c * 32 + k] = (_Float16)Wd[r];
    }
}

// ---------------------------------------------------------------------------
// QKV via MFMA (layer 0 only): xh @ WT -> q,k [bh][L][16], v^T [bh][16][L].
// ---------------------------------------------------------------------------
__global__ __launch_bounds__(256) void qkv_kernel(
    const _Float16* __restrict__ xh,
    const _Float16* __restrict__ qT, const _Float16* __restrict__ kT,
    const _Float16* __restrict__ vT,
    const float* __restrict__ bq, const float* __restrict__ bk,
    const float* __restrict__ bv,
    _Float16* __restrict__ qo, _Float16* __restrict__ ko, _Float16* __restrict__ vt)
{
    const int t = threadIdx.x, wv = t >> 6, lane = t & 63, lo = lane & 15, hi = lane >> 4;
    const int row0 = blockIdx.x * 64 + wv * 16;
    const int b = row0 >> 10, l0 = row0 & 1023;

    f16x4 a[4];
    #pragma unroll
    for (int kk = 0; kk < 4; kk++)
        a[kk] = *(const f16x4*)(xh + (row0 + lo) * 64 + kk * 16 + 4 * hi);

    #pragma unroll
    for (int m = 0; m < 3; m++) {
        const _Float16* WT = m == 0 ? qT : m == 1 ? kT : vT;
        const float* bias  = m == 0 ? bq : m == 1 ? bk : bv;
        #pragma unroll
        for (int h = 0; h < 4; h++) {
            float bb = bias[h * 16 + lo];
            f32x4 acc = { bb, bb, bb, bb };
            #pragma unroll
            for (int kk = 0; kk < 4; kk++) {
                f16x4 bf = *(const f16x4*)(WT + (h * 16 + lo) * 64 + kk * 16 + 4 * hi);
                acc = MFMA16(a[kk], bf, acc);
            }
            int bh = b * 4 + h;
            if (m < 2) {
                _Float16* dst = (m == 0 ? qo : ko) + (bh * Lc + l0 + 4 * hi) * 16 + lo;
                dst[0]  = (_Float16)acc[0];
                dst[16] = (_Float16)acc[1];
                dst[32] = (_Float16)acc[2];
                dst[48] = (_Float16)acc[3];
            } else {
                h16x2 p0 = __builtin_amdgcn_cvt_pkrtz(acc[0], acc[1]);
                h16x2 p1 = __builtin_amdgcn_cvt_pkrtz(acc[2], acc[3]);
                f16x4 o; o[0] = p0[0]; o[1] = p0[1]; o[2] = p1[0]; o[3] = p1[1];
                *(f16x4*)(vt + (bh * 16 + lo) * Lc + l0 + 4 * hi) = o;
            }
        }
    }
}

// ---------------------------------------------------------------------------
// FUSED per-layer kernel (r15 structure + F16 T-rings):
// block = (b, 64-row l-tile), 4 waves = 4 heads. Phase 1: 4-frag MFMA
// attention with deferred-exp pipeline; T-rings stored as f16 (b64 writes,
// u16 gathers) to cut LDS bank conflicts ~10x (r13 measurement).
// ctx stashed to LDS. Barrier. Phase 2: Wo-proj + resid + LN1 + FFN(gelu)
// + resid + LN2 + (optionally) next layer's QKV.
// LDS: Tmem[4 waves][3328 floats]: f16 rings 4x832 f16 during phase 1;
// after, wave-private ctx slice (512 fl), x1s (544 fl), ins (288 fl).
// ---------------------------------------------------------------------------
__global__ __launch_bounds__(256) void layer_kernel(
    const _Float16* __restrict__ qg, const _Float16* __restrict__ kg,
    const _Float16* __restrict__ vtg, const _Float16* __restrict__ relh,
    const float* __restrict__ resid,
    const _Float16* __restrict__ woT, const float* __restrict__ bo,
    const float* __restrict__ g1, const float* __restrict__ b1,
    const _Float16* __restrict__ wiT, const float* __restrict__ bi,
    const _Float16* __restrict__ wdT, const float* __restrict__ bd,
    const float* __restrict__ g2, const float* __restrict__ b2,
    float* __restrict__ xout,
    int doq,
    const _Float16* __restrict__ qT, const _Float16* __restrict__ kT,
    const _Float16* __restrict__ vT,
    const float* __restrict__ bq, const float* __restrict__ bk,
    const float* __restrict__ bv,
    _Float16* __restrict__ qo, _Float16* __restrict__ ko, _Float16* __restrict__ vo)
{
    __shared__ float Tmem[4 * 3328];
    const int tid = threadIdx.x;
    const int wv = tid >> 6, lane = tid & 63;
    const int b  = blockIdx.x & 31;            // same-b blocks share XCD (32%8==0)
    const int l0 = (blockIdx.x >> 5) * 64;
    const int bh = b * 4 + wv;
    const int lo = lane & 15, hi = lane >> 4;
    float* wbase = Tmem + wv * 3328;

    // ================= phase 1: attention (4-frag, deferred-exp, f16 rings) =====
    {
        const _Float16 qscale = (_Float16)0.36067376022224085f;   // 0.25*log2(e)
        f16x4 qf[4];
        #pragma unroll
        for (int i = 0; i < 4; i++) {
            qf[i] = *(const f16x4*)(qg + (bh * Lc + l0 + 16 * i + lo) * 16 + 4 * hi);
            #pragma unroll
            for (int j = 0; j < 4; j++) qf[i][j] *= qscale;
        }

        const int o = 12 + lo - 4 * hi;       // gather base offset, in [0,27]
        _Float16* ringh = (_Float16*)wbase;   // 4 rings x 832 f16, stride 52

        _Float16* wrE[4]; _Float16* wrO[4];
        const _Float16* rdE[4]; const _Float16* rdO[4];
        #pragma unroll
        for (int i = 0; i < 4; i++) {
            _Float16* ring = ringh + i * 832;
            const int phiE = 16 * (i & 1);
            const int phiO = 16 - phiE;
            wrE[i] = ring + lo * 52 + phiE + 4 * hi;
            wrO[i] = ring + lo * 52 + phiO + 4 * hi;
            rdE[i] = ring + lo * 52 + phiE + o;
            rdO[i] = ring + lo * 52 + phiO + o;
        }

        const _Float16* rbase = relh + 4 * hi;
        auto ldrel = [&](int row) {
            row = row > 2046 ? 2046 : row;   // clamped rows are never gathered
            return *(const f16x4*)(rbase + row * 16);
        };
        auto t_store = [&](f16x4 rf, f16x4 q, _Float16* wr, bool mir) {
            f32x4 z = { 0.f, 0.f, 0.f, 0.f };
            f32x4 tt = MFMA16(rf, q, z);
            h16x2 t0 = __builtin_amdgcn_cvt_pkrtz(tt[0], tt[1]);
            h16x2 t1 = __builtin_amdgcn_cvt_pkrtz(tt[2], tt[3]);
            f16x4 tv; tv[0] = t0[0]; tv[1] = t0[1]; tv[2] = t1[0]; tv[3] = t1[1];
            *(f16x4*)(wr) = tv;
            if (mir) *(f16x4*)(wr + 32) = tv;
        };

        f16x4 P[6];
        #pragma unroll
        for (int k = 0; k < 6; k++) P[k] = ldrel(l0 + 16 * k + lo);
        #pragma unroll
        for (int i = 0; i < 4; i++) {
            t_store(P[i],     qf[i], wrE[i], (i & 1) == 0);
            t_store(P[i + 1], qf[i], wrO[i], (i & 1) == 1);
        }
        f16x4 rc0 = P[2], rc1 = P[3], rc2 = P[4], rc3 = P[5];
        int rrow = l0 + 96 + lo;

        // gather si for step 0 (parity E); cvt f16->f32
        f32x4 si[4];
        #pragma unroll
        for (int i = 0; i < 4; i++) {
            const _Float16* rd = rdE[i];
            si[i][0] = (float)rd[3]; si[i][1] = (float)rd[2];
            si[i][2] = (float)rd[1]; si[i][3] = (float)rd[0];
        }

        const _Float16* kp = kg  + (bh * Lc + 1008 + lo) * 16 + 4 * hi;
        const _Float16* vp = vtg + (bh * 16 + lo) * Lc + 1008 + 4 * hi;
        f16x4 kf0 = *(const f16x4*)kp;
        f16x4 vf0 = *(const f16x4*)vp;
        kp -= 256; vp -= 16;
        f16x4 kf1 = *(const f16x4*)kp;
        f16x4 vf1 = *(const f16x4*)vp;

        f32x4 ot[4];
        float dd[4] = { 0.f, 0.f, 0.f, 0.f };
        #pragma unroll
        for (int i = 0; i < 4; i++) ot[i] = f32x4{ 0.f, 0.f, 0.f, 0.f };

        // prologue S(0)
        f32x4 s_cur[4];
        #pragma unroll
        for (int i = 0; i < 4; i++)
            s_cur[i] = MFMA16(kf0, qf[i], si[i]);

        #pragma unroll 2
        for (int t = 0; t < 64; ++t) {
            // issue loads for step t+2 (tail over/under-reads stay inside d_ws)
            kp -= 256; vp -= 16;
            f16x4 kf2 = *(const f16x4*)kp;
            f16x4 vf2 = *(const f16x4*)vp;
            f16x4 r4 = ldrel(rrow); rrow += 16;

            // write T tiles for step t+2 (frag i uses R(t+i)); mirror iff phi==0
            t_store(rc0, qf[0], (t & 1) ? wrO[0] : wrE[0], (t & 1) == 0);
            t_store(rc1, qf[1], (t & 1) ? wrO[1] : wrE[1], (t & 1) == 1);
            t_store(rc2, qf[2], (t & 1) ? wrO[2] : wrE[2], (t & 1) == 0);
            t_store(rc3, qf[3], (t & 1) ? wrO[3] : wrE[3], (t & 1) == 1);

            // gather si for step t+1 (reads tiles t+1, t+2; t+2 just written;
            // same-wave LDS is in-order). Parity of t+1 = opposite of t.
            #pragma unroll
            for (int i = 0; i < 4; i++) {
                const _Float16* rd = (t & 1) ? rdE[i] : rdO[i];
                si[i][0] = (float)rd[3]; si[i][1] = (float)rd[2];
                si[i][2] = (float)rd[1]; si[i][3] = (float)rd[0];
            }

            // exp/pack/den for step t (covers gather + S(t+1) input latency)
            h16x2 pa_[4], pb_[4];
            #pragma unroll
            for (int i = 0; i < 4; i++) {
                float e0 = EXP2(s_cur[i][0]), e1 = EXP2(s_cur[i][1]);
                float e2 = EXP2(s_cur[i][2]), e3 = EXP2(s_cur[i][3]);
                pa_[i] = __builtin_amdgcn_cvt_pkrtz(e0, e1);
                pb_[i] = __builtin_amdgcn_cvt_pkrtz(e2, e3);
                dd[i] = fdot2_acc(pa_[i], dd[i]);
                dd[i] = fdot2_acc(pb_[i], dd[i]);
            }

            // PV(t)
            #pragma unroll
            for (int i = 0; i < 4; i++) {
                f16x4 pf;
                pf[0] = pa_[i][0]; pf[1] = pa_[i][1];
                pf[2] = pb_[i][0]; pf[3] = pb_[i][1];
                ot[i] = MFMA16(vf0, pf, ot[i]);
            }

            // issue S(t+1) last: its latency is covered by the next
            // iteration's loads + T-stores before exp consumes it
            #pragma unroll
            for (int i = 0; i < 4; i++)
                s_cur[i] = MFMA16(kf1, qf[i], si[i]);

            kf1 = kf2;
            vf0 = vf1; vf1 = vf2;
            rc0 = rc1; rc1 = rc2; rc2 = rc3; rc3 = r4;
        }

        // stash ctx into own wave region (rings are dead)
        _Float16* ctxw = (_Float16*)wbase;      // [64 rows][16 dims] f16
        #pragma unroll
        for (int i = 0; i < 4; i++) {
            float den = dd[i];
            den += __shfl_xor(den, 16);
            den += __shfl_xor(den, 32);
            const float inv = 1.f / den;
            h16x2 o0 = __builtin_amdgcn_cvt_pkrtz(ot[i][0] * inv, ot[i][1] * inv);
            h16x2 o1 = __builtin_amdgcn_cvt_pkrtz(ot[i][2] * inv, ot[i][3] * inv);
            f16x4 o4; o4[0] = o0[0]; o4[1] = o0[1]; o4[2] = o1[0]; o4[3] = o1[1];
            *(f16x4*)(ctxw + (16 * i + lo) * 16 + 4 * hi) = o4;
        }
    }
    __syncthreads();

    // ================= phase 2: layer tail =================
    const _Float16* ctxs = (const _Float16*)Tmem;  // region w: Tmem + w*3328 floats
    const int row0g = b * Lc + l0 + wv * 16;       // global row

    // ---- proj: C1 = ctx@Wo + bo + resid (ctx from LDS)
    f16x4 a[4];
    #pragma unroll
    for (int kk = 0; kk < 4; kk++)
        a[kk] = *(const f16x4*)(ctxs + kk * 6656 + (wv * 16 + lo) * 16 + 4 * hi);

    float c1[4][4];
    #pragma unroll
    for (int w = 0; w < 4; w++) {
        float bb = bo[w * 16 + lo];
        f32x4 acc;
        #pragma unroll
        for (int j = 0; j < 4; j++)
            acc[j] = bb + resid[(row0g + 4 * hi + j) * 64 + w * 16 + lo];
        #pragma unroll
        for (int kk = 0; kk < 4; kk++) {
            f16x4 bf = *(const f16x4*)(woT + (w * 16 + lo) * 64 + kk * 16 + 4 * hi);
            acc = MFMA16(a[kk], bf, acc);
        }
        #pragma unroll
        for (int j = 0; j < 4; j++) c1[w][j] = acc[j];
    }

    // ---- LN1 -> x1
    float x1[4][4];
    {
        float gg[4], bb2[4];
        #pragma unroll
        for (int w = 0; w < 4; w++) { gg[w] = g1[w * 16 + lo]; bb2[w] = b1[w * 16 + lo]; }
        #pragma unroll
        for (int j = 0; j < 4; j++) {
            float s = c1[0][j] + c1[1][j] + c1[2][j] + c1[3][j];
            float q = c1[0][j]*c1[0][j] + c1[1][j]*c1[1][j] + c1[2][j]*c1[2][j] + c1[3][j]*c1[3][j];
            #pragma unroll
            for (int off = 1; off < 16; off <<= 1) { s += __shfl_xor(s, off); q += __shfl_xor(q, off); }
            float m  = s * (1.f / 64.f);
            float vr = q * (1.f / 64.f) - m * m;
            float rs = rsqrtf(vr + 1e-12f);
            #pragma unroll
            for (int w = 0; w < 4; w++) x1[w][j] = (c1[w][j] - m) * rs * gg[w] + bb2[w];
        }
    }

    // wave-private transpose buffers inside own region (past ctx slice)
    _Float16* xsp = (_Float16*)(wbase + 512);        // 16*68 f16
    _Float16* isp = (_Float16*)(wbase + 512 + 544);  // 16*36 f16

    #pragma unroll
    for (int w = 0; w < 4; w++)
        #pragma unroll
        for (int j = 0; j < 4; j++)
            xsp[(4 * hi + j) * 68 + w * 16 + lo] = (_Float16)x1[w][j];
    f16x4 a2[4];
    #pragma unroll
    for (int kk = 0; kk < 4; kk++)
        a2[kk] = *(const f16x4*)(xsp + lo * 68 + kk * 16 + 4 * hi);

    // ---- FFN1 + gelu
    float it[2][4];
    #pragma unroll
    for (int w = 0; w < 2; w++) {
        float bb = bi[w * 16 + lo];
        f32x4 acc = { bb, bb, bb, bb };
        #pragma unroll
        for (int kk = 0; kk < 4; kk++) {
            f16x4 bf = *(const f16x4*)(wiT + (w * 16 + lo) * 64 + kk * 16 + 4 * hi);
            acc = MFMA16(a2[kk], bf, acc);
        }
        #pragma unroll
        for (int j = 0; j < 4; j++) {
            float v = acc[j];
            it[w][j] = 0.5f * v * (1.f + erff(v * 0.70710678118654752f));
        }
    }

    #pragma unroll
    for (int w = 0; w < 2; w++)
        #pragma unroll
        for (int j = 0; j < 4; j++)
            isp[(4 * hi + j) * 36 + w * 16 + lo] = (_Float16)it[w][j];
    f16x4 a3[2];
    #pragma unroll
    for (int kk = 0; kk < 2; kk++)
        a3[kk] = *(const f16x4*)(isp + lo * 36 + kk * 16 + 4 * hi);

    // ---- FFN2 + bd + x1 residual
    float c2[4][4];
    #pragma unroll
    for (int w = 0; w < 4; w++) {
        float bb = bd[w * 16 + lo];
        f32x4 acc;
        #pragma unroll
        for (int j = 0; j < 4; j++) acc[j] = bb + x1[w][j];
        #pragma unroll
        for (int kk = 0; kk < 2; kk++) {
            f16x4 bf = *(const f16x4*)(wdT + (w * 16 + lo) * 32 + kk * 16 + 4 * hi);
            acc = MFMA16(a3[kk], bf, acc);
        }
        #pragma unroll
        for (int j = 0; j < 4; j++) c2[w][j] = acc[j];
    }

    // ---- LN2 -> xout (f32) + x2 (registers)
    float x2[4][4];
    {
        float gg[4], bb2[4];
        #pragma unroll
        for (int w = 0; w < 4; w++) { gg[w] = g2[w * 16 + lo]; bb2[w] = b2[w * 16 + lo]; }
        #pragma unroll
        for (int j = 0; j < 4; j++) {
            float s = c2[0][j] + c2[1][j] + c2[2][j] + c2[3][j];
            float q = c2[0][j]*c2[0][j] + c2[1][j]*c2[1][j] + c2[2][j]*c2[2][j] + c2[3][j]*c2[3][j];
            #pragma unroll
            for (int off = 1; off < 16; off <<= 1) { s += __shfl_xor(s, off); q += __shfl_xor(q, off); }
            float m  = s * (1.f / 64.f);
            float vr = q * (1.f / 64.f) - m * m;
            float rs = rsqrtf(vr + 1e-12f);
            #pragma unroll
            for (int w = 0; w < 4; w++) {
                float xv = (c2[w][j] - m) * rs * gg[w] + bb2[w];
                x2[w][j] = xv;
                xout[(row0g + 4 * hi + j) * 64 + w * 16 + lo] = xv;
            }
        }
    }

    if (!doq) return;

    // ---- next layer's QKV (transpose x2 through xsp; same-wave order)
    #pragma unroll
    for (int w = 0; w < 4; w++)
        #pragma unroll
        for (int j = 0; j < 4; j++)
            xsp[(4 * hi + j) * 68 + w * 16 + lo] = (_Float16)x2[w][j];
    f16x4 aq[4];
    #pragma unroll
    for (int kk = 0; kk < 4; kk++)
        aq[kk] = *(const f16x4*)(xsp + lo * 68 + kk * 16 + 4 * hi);

    const int bb_ = row0g >> 10, l0q = row0g & 1023;
    #pragma unroll
    for (int m = 0; m < 3; m++) {
        const _Float16* WT = m == 0 ? qT : m == 1 ? kT : vT;
        const float* bias  = m == 0 ? bq : m == 1 ? bk : bv;
        #pragma unroll
        for (int h = 0; h < 4; h++) {
            float bb = bias[h * 16 + lo];
            f32x4 acc = { bb, bb, bb, bb };
            #pragma unroll
            for (int kk = 0; kk < 4; kk++) {
                f16x4 bf = *(const f16x4*)(WT + (h * 16 + lo) * 64 + kk * 16 + 4 * hi);
                acc = MFMA16(aq[kk], bf, acc);
            }
            int bhn = bb_ * 4 + h;
            if (m < 2) {
                _Float16* dst = (m == 0 ? qo : ko) + (bhn * Lc + l0q + 4 * hi) * 16 + lo;
                dst[0]  = (_Float16)acc[0];
                dst[16] = (_Float16)acc[1];
                dst[32] = (_Float16)acc[2];
                dst[48] = (_Float16)acc[3];
            } else {
                h16x2 p0 = __builtin_amdgcn_cvt_pkrtz(acc[0], acc[1]);
                h16x2 p1 = __builtin_amdgcn_cvt_pkrtz(acc[2], acc[3]);
                f16x4 o; o[0] = p0[0]; o[1] = p0[1]; o[2] = p1[0]; o[3] = p1[1];
                *(f16x4*)(vo + (bhn * 16 + lo) * Lc + l0q + 4 * hi) = o;
            }
        }
    }
}

// ---------------------------------------------------------------------------
// Final classifier, dropping l==0.
// ---------------------------------------------------------------------------
__global__ __launch_bounds__(256) void final_kernel(
    const float* __restrict__ x, const float* __restrict__ fcw,
    const float* __restrict__ fcb, float* __restrict__ out)
{
    int idx = blockIdx.x * 256 + threadIdx.x;
    if (idx >= Bc * 1023 * 6) return;
    int j = idx % 6;
    int rest = idx / 6;
    int l = rest % 1023 + 1;
    int b = rest / 1023;
    const float* xr = x + (b * Lc + l) * 64;
    float acc = fcb[j];
    for (int k = 0; k < 64; ++k) acc += xr[k] * fcw[k * 6 + j];
    out[idx] = acc;
}

// ---------------------------------------------------------------------------
extern "C" void kernel_launch(void* const* d_in, const int* in_sizes, int n_in,
                              void* d_out, int out_size, void* d_ws, size_t ws_size,
                              hipStream_t stream)
{
    (void)in_sizes; (void)n_in; (void)out_size; (void)ws_size;
    const float* features = (const float*)d_in[0];
    const float* Wq  = (const float*)d_in[1];
    const float* bq  = (const float*)d_in[2];
    const float* Wk  = (const float*)d_in[3];
    const float* bk  = (const float*)d_in[4];
    const float* Wv  = (const float*)d_in[5];
    const float* bv  = (const float*)d_in[6];
    const float* Wo  = (const float*)d_in[7];
    const float* bo  = (const float*)d_in[8];
    const float* g1  = (const float*)d_in[9];
    const float* b1  = (const float*)d_in[10];
    const float* Wi  = (const float*)d_in[11];
    const float* bi  = (const float*)d_in[12];
    const float* Wd  = (const float*)d_in[13];
    const float* bd  = (const float*)d_in[14];
    const float* g2  = (const float*)d_in[15];
    const float* b2  = (const float*)d_in[16];
    const float* rel = (const float*)d_in[17];
    const float* fcw = (const float*)d_in[18];
    const float* fcb = (const float*)d_in[19];
    float* out = (float*)d_out;

    char* ws = (char*)d_ws;
    float*    xbuf = (float*)(ws);                    // 8 MB
    _Float16* qh1  = (_Float16*)(ws + ( 8u << 20));   // 4 MB (aliases xh)
    _Float16* xh   = qh1;                             // layer-0 f16 features
    _Float16* kh1  = (_Float16*)(ws + (12u << 20));
    _Float16* vt1  = (_Float16*)(ws + (16u << 20));
    _Float16* qh0  = (_Float16*)(ws + (20u << 20));
    _Float16* kh0  = (_Float16*)(ws + (24u << 20));
    _Float16* vt0  = (_Float16*)(ws + (28u << 20));
    _Float16* relh = (_Float16*)(ws + (32u << 20));            // 262 KB
    _Float16* wt   = (_Float16*)(ws + (32u << 20) + (512u << 10)); // 160 KB

    prep_kernel<<<2048, 256, 0, stream>>>(features, rel, Wq, Wk, Wv, Wo, Wi, Wd,
                                          xh, relh, wt);
    qkv_kernel<<<512, 256, 0, stream>>>(xh,
        wt, wt + 16384, wt + 32768, bq, bk, bv, qh0, kh0, vt0);

    for (int i = 0; i < 4; ++i) {
        const float* resid = (i == 0) ? features : xbuf;
        const int ni = (i < 3) ? (i + 1) : 3;
        const _Float16* qin = (i & 1) ? qh1 : qh0;
        const _Float16* kin = (i & 1) ? kh1 : kh0;
        const _Float16* vin = (i & 1) ? vt1 : vt0;
        _Float16* qout = (i & 1) ? qh0 : qh1;
        _Float16* kout = (i & 1) ? kh0 : kh1;
        _Float16* vout = (i & 1) ? vt0 : vt1;

        layer_kernel<<<512, 256, 0, stream>>>(qin, kin, vin,
            relh + i * 2047 * 16, resid,
            wt + 49152 + i * 4096, bo + i * 64, g1 + i * 64, b1 + i * 64,
            wt + 65536 + i * 2048, bi + i * 32,
            wt + 73728 + i * 2048, bd + i * 64, g2 + i * 64, b2 + i * 64,
            xbuf,
            (i < 3) ? 1 : 0,
            wt + ni * 4096, wt + 16384 + ni * 4096, wt + 32768 + ni * 4096,
            bq + ni * 64, bk + ni * 64, bv + ni * 64,
            qout, kout, vout);
    }
    final_kernel<<<768, 256, 0, stream>>>(xbuf, fcw, fcb, out);
}

// Round 17
// 262.769 us; speedup vs baseline: 1.3950x; 1.3950x over previous
//
#include <hip/hip_runtime.h>
#include <math.h>

static constexpr int Bc = 32;
static constexpr int Lc = 1024;

typedef _Float16 f16x4 __attribute__((ext_vector_type(4)));
typedef __fp16   h16x2 __attribute__((ext_vector_type(2)));   // cvt_pkrtz result type
typedef float    f32x4 __attribute__((ext_vector_type(4)));

#define MFMA16(a, b, c) __builtin_amdgcn_mfma_f32_16x16x16f16((a), (b), (c), 0, 0, 0)

#if __has_builtin(__builtin_amdgcn_exp2f)
#define EXP2(x) __builtin_amdgcn_exp2f(x)
#else
#define EXP2(x) exp2f(x)
#endif

// ---------------------------------------------------------------------------
// Fused prep: features f32->f16, rel f32->f16, weight transpose+convert.
// ---------------------------------------------------------------------------
__global__ __launch_bounds__(256) void prep_kernel(
    const float* __restrict__ features, const float* __restrict__ rel,
    const float* __restrict__ Wq, const float* __restrict__ Wk,
    const float* __restrict__ Wv, const float* __restrict__ Wo,
    const float* __restrict__ Wi, const float* __restrict__ Wd,
    _Float16* __restrict__ xh, _Float16* __restrict__ relh,
    _Float16* __restrict__ wt)
{
    int i = blockIdx.x * 256 + threadIdx.x;          // 0..524287
    {
        float4 v = ((const float4*)features)[i];
        h16x2 a = __builtin_amdgcn_cvt_pkrtz(v.x, v.y);
        h16x2 b = __builtin_amdgcn_cvt_pkrtz(v.z, v.w);
        f16x4 o; o[0] = a[0]; o[1] = a[1]; o[2] = b[0]; o[3] = b[1];
        ((f16x4*)xh)[i] = o;
    }
    if (i < 32752) {
        float4 v = ((const float4*)rel)[i];
        h16x2 a = __builtin_amdgcn_cvt_pkrtz(v.x, v.y);
        h16x2 b = __builtin_amdgcn_cvt_pkrtz(v.z, v.w);
        f16x4 o; o[0] = a[0]; o[1] = a[1]; o[2] = b[0]; o[3] = b[1];
        ((f16x4*)relh)[i] = o;
    }
    if (i < 65536) {
        int which = i >> 14, r = i & 16383;
        int m = r >> 12, k = (r >> 6) & 63, c = r & 63;
        const float* src = which == 0 ? Wq : which == 1 ? Wk : which == 2 ? Wv : Wo;
        wt[which * 16384 + m * 4096 + c * 64 + k] = (_Float16)src[r];
    } else if (i < 73728) {
        int r = i - 65536;                    // Wi [4][64][32]
        int m = r >> 11, k = (r >> 5) & 63, c = r & 31;
        wt[65536 + m * 2048 + c * 64 + k] = (_Float16)Wi[r];
    } else if (i < 81920) {
        int r = i - 73728;                    // Wd [4][32][64]
        int m = r >> 11, k = (r >> 6) & 31, c = r & 63;
        wt[73728 + m * 2048 + c * 32 + k] = (_Float16)Wd[r];
    }
}

// ---------------------------------------------------------------------------
// QKV via MFMA (layer 0 only): xh @ WT -> q,k [bh][L][16], v^T [bh][16][L].
// ---------------------------------------------------------------------------
__global__ __launch_bounds__(256) void qkv_kernel(
    const _Float16* __restrict__ xh,
    const _Float16* __restrict__ qT, const _Float16* __restrict__ kT,
    const _Float16* __restrict__ vT,
    const float* __restrict__ bq, const float* __restrict__ bk,
    const float* __restrict__ bv,
    _Float16* __restrict__ qo, _Float16* __restrict__ ko, _Float16* __restrict__ vt)
{
    const int t = threadIdx.x, wv = t >> 6, lane = t & 63, lo = lane & 15, hi = lane >> 4;
    const int row0 = blockIdx.x * 64 + wv * 16;
    const int b = row0 >> 10, l0 = row0 & 1023;

    f16x4 a[4];
    #pragma unroll
    for (int kk = 0; kk < 4; kk++)
        a[kk] = *(const f16x4*)(xh + (row0 + lo) * 64 + kk * 16 + 4 * hi);

    #pragma unroll
    for (int m = 0; m < 3; m++) {
        const _Float16* WT = m == 0 ? qT : m == 1 ? kT : vT;
        const float* bias  = m == 0 ? bq : m == 1 ? bk : bv;
        #pragma unroll
        for (int h = 0; h < 4; h++) {
            float bb = bias[h * 16 + lo];
            f32x4 acc = { bb, bb, bb, bb };
            #pragma unroll
            for (int kk = 0; kk < 4; kk++) {
                f16x4 bf = *(const f16x4*)(WT + (h * 16 + lo) * 64 + kk * 16 + 4 * hi);
                acc = MFMA16(a[kk], bf, acc);
            }
            int bh = b * 4 + h;
            if (m < 2) {
                _Float16* dst = (m == 0 ? qo : ko) + (bh * Lc + l0 + 4 * hi) * 16 + lo;
                dst[0]  = (_Float16)acc[0];
                dst[16] = (_Float16)acc[1];
                dst[32] = (_Float16)acc[2];
                dst[48] = (_Float16)acc[3];
            } else {
                h16x2 p0 = __builtin_amdgcn_cvt_pkrtz(acc[0], acc[1]);
                h16x2 p1 = __builtin_amdgcn_cvt_pkrtz(acc[2], acc[3]);
                f16x4 o; o[0] = p0[0]; o[1] = p0[1]; o[2] = p1[0]; o[3] = p1[1];
                *(f16x4*)(vt + (bh * 16 + lo) * Lc + l0 + 4 * hi) = o;
            }
        }
    }
}

// ---------------------------------------------------------------------------
// FUSED per-layer kernel (r11 exact): block = (b, 64-row l-tile), 4 waves =
// 4 heads. Phase 1 (per wave): 4-frag MFMA attention with f32 T-rings,
// 2-deep K/V prefetch, 1-ahead rel-gather; ctx stashed to LDS.
// Barrier. Phase 2 (per wave, 16 rows): Wo-proj + resid + LN1 + FFN(gelu) +
// resid + LN2 + (optionally) next layer's QKV from registers/LDS.
// LDS: Tmem[4 waves][3328 floats]: rings 4x832 during phase 1; after the
// loop, wave-private ctx slice (512 fl), x1s (544 fl), ins (288 fl).
// ---------------------------------------------------------------------------
__global__ __launch_bounds__(256) void layer_kernel(
    const _Float16* __restrict__ qg, const _Float16* __restrict__ kg,
    const _Float16* __restrict__ vtg, const _Float16* __restrict__ relh,
    const float* __restrict__ resid,
    const _Float16* __restrict__ woT, const float* __restrict__ bo,
    const float* __restrict__ g1, const float* __restrict__ b1,
    const _Float16* __restrict__ wiT, const float* __restrict__ bi,
    const _Float16* __restrict__ wdT, const float* __restrict__ bd,
    const float* __restrict__ g2, const float* __restrict__ b2,
    float* __restrict__ xout,
    int doq,
    const _Float16* __restrict__ qT, const _Float16* __restrict__ kT,
    const _Float16* __restrict__ vT,
    const float* __restrict__ bq, const float* __restrict__ bk,
    const float* __restrict__ bv,
    _Float16* __restrict__ qo, _Float16* __restrict__ ko, _Float16* __restrict__ vo)
{
    __shared__ float Tmem[4 * 3328];
    const int tid = threadIdx.x;
    const int wv = tid >> 6, lane = tid & 63;
    const int b  = blockIdx.x & 31;            // same-b blocks share XCD (32%8==0)
    const int l0 = (blockIdx.x >> 5) * 64;
    const int bh = b * 4 + wv;
    const int lo = lane & 15, hi = lane >> 4;
    float* wbase = Tmem + wv * 3328;

    // ================= phase 1: attention (r10/r11 body) =================
    {
        const _Float16 qscale = (_Float16)0.36067376022224085f;   // 0.25*log2(e)
        f16x4 qf[4];
        #pragma unroll
        for (int i = 0; i < 4; i++) {
            qf[i] = *(const f16x4*)(qg + (bh * Lc + l0 + 16 * i + lo) * 16 + 4 * hi);
            #pragma unroll
            for (int j = 0; j < 4; j++) qf[i][j] *= qscale;
        }

        const int o = 12 + lo - 4 * hi;       // gather base offset, in [0,27]

        float* wrE[4]; float* wrO[4]; const float* rdE[4]; const float* rdO[4];
        #pragma unroll
        for (int i = 0; i < 4; i++) {
            float* ring = wbase + i * 832;
            const int phiE = 16 * (i & 1);
            const int phiO = 16 - phiE;
            wrE[i] = ring + lo * 52 + phiE + 4 * hi;
            wrO[i] = ring + lo * 52 + phiO + 4 * hi;
            rdE[i] = ring + lo * 52 + phiE + o;
            rdO[i] = ring + lo * 52 + phiO + o;
        }

        const _Float16* rbase = relh + 4 * hi;
        auto ldrel = [&](int row) {
            row = row > 2046 ? 2046 : row;   // clamped rows are never gathered
            return *(const f16x4*)(rbase + row * 16);
        };
        auto t_store = [&](f16x4 rf, f16x4 q, float* wr, bool mir) {
            f32x4 z = { 0.f, 0.f, 0.f, 0.f };
            f32x4 tt = MFMA16(rf, q, z);
            *(f32x4*)(wr) = tt;
            if (mir) *(f32x4*)(wr + 32) = tt;
        };

        f16x4 P[6];
        #pragma unroll
        for (int k = 0; k < 6; k++) P[k] = ldrel(l0 + 16 * k + lo);
        #pragma unroll
        for (int i = 0; i < 4; i++) {
            t_store(P[i],     qf[i], wrE[i], (i & 1) == 0);
            t_store(P[i + 1], qf[i], wrO[i], (i & 1) == 1);
        }
        f16x4 rc0 = P[2], rc1 = P[3], rc2 = P[4], rc3 = P[5];
        int rrow = l0 + 96 + lo;

        f32x4 si[4];
        #pragma unroll
        for (int i = 0; i < 4; i++) {
            const float* rd = rdE[i];
            si[i][0] = rd[3]; si[i][1] = rd[2]; si[i][2] = rd[1]; si[i][3] = rd[0];
        }

        const _Float16* kp = kg  + (bh * Lc + 1008 + lo) * 16 + 4 * hi;
        const _Float16* vp = vtg + (bh * 16 + lo) * Lc + 1008 + 4 * hi;
        f16x4 kf0 = *(const f16x4*)kp;
        f16x4 vf0 = *(const f16x4*)vp;
        kp -= 256; vp -= 16;
        f16x4 kf1 = *(const f16x4*)kp;
        f16x4 vf1 = *(const f16x4*)vp;

        f32x4 ot[4], d[4];
        #pragma unroll
        for (int i = 0; i < 4; i++) {
            ot[i] = f32x4{ 0.f, 0.f, 0.f, 0.f };
            d[i]  = f32x4{ 0.f, 0.f, 0.f, 0.f };
        }

        #pragma unroll 2
        for (int t = 0; t < 64; ++t) {
            kp -= 256; vp -= 16;
            f16x4 kf2 = *(const f16x4*)kp;
            f16x4 vf2 = *(const f16x4*)vp;
            f16x4 r4 = ldrel(rrow); rrow += 16;

            f32x4 s[4];
            #pragma unroll
            for (int i = 0; i < 4; i++)
                s[i] = MFMA16(kf0, qf[i], si[i]);

            float e[4][4];
            #pragma unroll
            for (int i = 0; i < 4; i++)
                #pragma unroll
                for (int j = 0; j < 4; j++) {
                    e[i][j] = EXP2(s[i][j]);
                    d[i][j] += e[i][j];
                }

            t_store(rc0, qf[0], (t & 1) ? wrO[0] : wrE[0], (t & 1) == 0);
            t_store(rc1, qf[1], (t & 1) ? wrO[1] : wrE[1], (t & 1) == 1);
            t_store(rc2, qf[2], (t & 1) ? wrO[2] : wrE[2], (t & 1) == 0);
            t_store(rc3, qf[3], (t & 1) ? wrO[3] : wrE[3], (t & 1) == 1);

            #pragma unroll
            for (int i = 0; i < 4; i++) {
                const float* rd = (t & 1) ? rdE[i] : rdO[i];
                si[i][0] = rd[3]; si[i][1] = rd[2]; si[i][2] = rd[1]; si[i][3] = rd[0];
            }

            #pragma unroll
            for (int i = 0; i < 4; i++) {
                h16x2 pa = __builtin_amdgcn_cvt_pkrtz(e[i][0], e[i][1]);
                h16x2 pb = __builtin_amdgcn_cvt_pkrtz(e[i][2], e[i][3]);
                f16x4 pf; pf[0] = pa[0]; pf[1] = pa[1]; pf[2] = pb[0]; pf[3] = pb[1];
                ot[i] = MFMA16(vf0, pf, ot[i]);
            }

            kf0 = kf1; kf1 = kf2;
            vf0 = vf1; vf1 = vf2;
            rc0 = rc1; rc1 = rc2; rc2 = rc3; rc3 = r4;
        }

        // stash ctx into own wave region (rings are dead)
        _Float16* ctxw = (_Float16*)wbase;      // [64 rows][16 dims] f16
        #pragma unroll
        for (int i = 0; i < 4; i++) {
            float den = (d[i][0] + d[i][1]) + (d[i][2] + d[i][3]);
            den += __shfl_xor(den, 16);
            den += __shfl_xor(den, 32);
            const float inv = 1.f / den;
            h16x2 o0 = __builtin_amdgcn_cvt_pkrtz(ot[i][0] * inv, ot[i][1] * inv);
            h16x2 o1 = __builtin_amdgcn_cvt_pkrtz(ot[i][2] * inv, ot[i][3] * inv);
            f16x4 o4; o4[0] = o0[0]; o4[1] = o0[1]; o4[2] = o1[0]; o4[3] = o1[1];
            *(f16x4*)(ctxw + (16 * i + lo) * 16 + 4 * hi) = o4;
        }
    }
    __syncthreads();

    // ================= phase 2: layer tail =================
    const _Float16* ctxs = (const _Float16*)Tmem;  // region w: Tmem + w*3328 floats
    const int row0g = b * Lc + l0 + wv * 16;       // global row

    // ---- proj: C1 = ctx@Wo + bo + resid (ctx from LDS)
    f16x4 a[4];
    #pragma unroll
    for (int kk = 0; kk < 4; kk++)
        a[kk] = *(const f16x4*)(ctxs + kk * 6656 + (wv * 16 + lo) * 16 + 4 * hi);

    float c1[4][4];
    #pragma unroll
    for (int w = 0; w < 4; w++) {
        float bb = bo[w * 16 + lo];
        f32x4 acc;
        #pragma unroll
        for (int j = 0; j < 4; j++)
            acc[j] = bb + resid[(row0g + 4 * hi + j) * 64 + w * 16 + lo];
        #pragma unroll
        for (int kk = 0; kk < 4; kk++) {
            f16x4 bf = *(const f16x4*)(woT + (w * 16 + lo) * 64 + kk * 16 + 4 * hi);
            acc = MFMA16(a[kk], bf, acc);
        }
        #pragma unroll
        for (int j = 0; j < 4; j++) c1[w][j] = acc[j];
    }

    // ---- LN1 -> x1
    float x1[4][4];
    {
        float gg[4], bb2[4];
        #pragma unroll
        for (int w = 0; w < 4; w++) { gg[w] = g1[w * 16 + lo]; bb2[w] = b1[w * 16 + lo]; }
        #pragma unroll
        for (int j = 0; j < 4; j++) {
            float s = c1[0][j] + c1[1][j] + c1[2][j] + c1[3][j];
            float q = c1[0][j]*c1[0][j] + c1[1][j]*c1[1][j] + c1[2][j]*c1[2][j] + c1[3][j]*c1[3][j];
            #pragma unroll
            for (int off = 1; off < 16; off <<= 1) { s += __shfl_xor(s, off); q += __shfl_xor(q, off); }
            float m  = s * (1.f / 64.f);
            float vr = q * (1.f / 64.f) - m * m;
            float rs = rsqrtf(vr + 1e-12f);
            #pragma unroll
            for (int w = 0; w < 4; w++) x1[w][j] = (c1[w][j] - m) * rs * gg[w] + bb2[w];
        }
    }

    // wave-private transpose buffers inside own region (past ctx slice)
    _Float16* xsp = (_Float16*)(wbase + 512);        // 16*68 f16
    _Float16* isp = (_Float16*)(wbase + 512 + 544);  // 16*36 f16

    #pragma unroll
    for (int w = 0; w < 4; w++)
        #pragma unroll
        for (int j = 0; j < 4; j++)
            xsp[(4 * hi + j) * 68 + w * 16 + lo] = (_Float16)x1[w][j];
    f16x4 a2[4];
    #pragma unroll
    for (int kk = 0; kk < 4; kk++)
        a2[kk] = *(const f16x4*)(xsp + lo * 68 + kk * 16 + 4 * hi);

    // ---- FFN1 + gelu
    float it[2][4];
    #pragma unroll
    for (int w = 0; w < 2; w++) {
        float bb = bi[w * 16 + lo];
        f32x4 acc = { bb, bb, bb, bb };
        #pragma unroll
        for (int kk = 0; kk < 4; kk++) {
            f16x4 bf = *(const f16x4*)(wiT + (w * 16 + lo) * 64 + kk * 16 + 4 * hi);
            acc = MFMA16(a2[kk], bf, acc);
        }
        #pragma unroll
        for (int j = 0; j < 4; j++) {
            float v = acc[j];
            it[w][j] = 0.5f * v * (1.f + erff(v * 0.70710678118654752f));
        }
    }

    #pragma unroll
    for (int w = 0; w < 2; w++)
        #pragma unroll
        for (int j = 0; j < 4; j++)
            isp[(4 * hi + j) * 36 + w * 16 + lo] = (_Float16)it[w][j];
    f16x4 a3[2];
    #pragma unroll
    for (int kk = 0; kk < 2; kk++)
        a3[kk] = *(const f16x4*)(isp + lo * 36 + kk * 16 + 4 * hi);

    // ---- FFN2 + bd + x1 residual
    float c2[4][4];
    #pragma unroll
    for (int w = 0; w < 4; w++) {
        float bb = bd[w * 16 + lo];
        f32x4 acc;
        #pragma unroll
        for (int j = 0; j < 4; j++) acc[j] = bb + x1[w][j];
        #pragma unroll
        for (int kk = 0; kk < 2; kk++) {
            f16x4 bf = *(const f16x4*)(wdT + (w * 16 + lo) * 32 + kk * 16 + 4 * hi);
            acc = MFMA16(a3[kk], bf, acc);
        }
        #pragma unroll
        for (int j = 0; j < 4; j++) c2[w][j] = acc[j];
    }

    // ---- LN2 -> xout (f32) + x2 (registers)
    float x2[4][4];
    {
        float gg[4], bb2[4];
        #pragma unroll
        for (int w = 0; w < 4; w++) { gg[w] = g2[w * 16 + lo]; bb2[w] = b2[w * 16 + lo]; }
        #pragma unroll
        for (int j = 0; j < 4; j++) {
            float s = c2[0][j] + c2[1][j] + c2[2][j] + c2[3][j];
            float q = c2[0][j]*c2[0][j] + c2[1][j]*c2[1][j] + c2[2][j]*c2[2][j] + c2[3][j]*c2[3][j];
            #pragma unroll
            for (int off = 1; off < 16; off <<= 1) { s += __shfl_xor(s, off); q += __shfl_xor(q, off); }
            float m  = s * (1.f / 64.f);
            float vr = q * (1.f / 64.f) - m * m;
            float rs = rsqrtf(vr + 1e-12f);
            #pragma unroll
            for (int w = 0; w < 4; w++) {
                float xv = (c2[w][j] - m) * rs * gg[w] + bb2[w];
                x2[w][j] = xv;
                xout[(row0g + 4 * hi + j) * 64 + w * 16 + lo] = xv;
            }
        }
    }

    if (!doq) return;

    // ---- next layer's QKV (transpose x2 through xsp; same-wave order)
    #pragma unroll
    for (int w = 0; w < 4; w++)
        #pragma unroll
        for (int j = 0; j < 4; j++)
            xsp[(4 * hi + j) * 68 + w * 16 + lo] = (_Float16)x2[w][j];
    f16x4 aq[4];
    #pragma unroll
    for (int kk = 0; kk < 4; kk++)
        aq[kk] = *(const f16x4*)(xsp + lo * 68 + kk * 16 + 4 * hi);

    const int bb_ = row0g >> 10, l0q = row0g & 1023;
    #pragma unroll
    for (int m = 0; m < 3; m++) {
        const _Float16* WT = m == 0 ? qT : m == 1 ? kT : vT;
        const float* bias  = m == 0 ? bq : m == 1 ? bk : bv;
        #pragma unroll
        for (int h = 0; h < 4; h++) {
            float bb = bias[h * 16 + lo];
            f32x4 acc = { bb, bb, bb, bb };
            #pragma unroll
            for (int kk = 0; kk < 4; kk++) {
                f16x4 bf = *(const f16x4*)(WT + (h * 16 + lo) * 64 + kk * 16 + 4 * hi);
                acc = MFMA16(aq[kk], bf, acc);
            }
            int bhn = bb_ * 4 + h;
            if (m < 2) {
                _Float16* dst = (m == 0 ? qo : ko) + (bhn * Lc + l0q + 4 * hi) * 16 + lo;
                dst[0]  = (_Float16)acc[0];
                dst[16] = (_Float16)acc[1];
                dst[32] = (_Float16)acc[2];
                dst[48] = (_Float16)acc[3];
            } else {
                h16x2 p0 = __builtin_amdgcn_cvt_pkrtz(acc[0], acc[1]);
                h16x2 p1 = __builtin_amdgcn_cvt_pkrtz(acc[2], acc[3]);
                f16x4 o; o[0] = p0[0]; o[1] = p0[1]; o[2] = p1[0]; o[3] = p1[1];
                *(f16x4*)(vo + (bhn * 16 + lo) * Lc + l0q + 4 * hi) = o;
            }
        }
    }
}

// ---------------------------------------------------------------------------
// Final classifier, dropping l==0.
// ---------------------------------------------------------------------------
__global__ __launch_bounds__(256) void final_kernel(
    const float* __restrict__ x, const float* __restrict__ fcw,
    const float* __restrict__ fcb, float* __restrict__ out)
{
    int idx = blockIdx.x * 256 + threadIdx.x;
    if (idx >= Bc * 1023 * 6) return;
    int j = idx % 6;
    int rest = idx / 6;
    int l = rest % 1023 + 1;
    int b = rest / 1023;
    const float* xr = x + (b * Lc + l) * 64;
    float acc = fcb[j];
    for (int k = 0; k < 64; ++k) acc += xr[k] * fcw[k * 6 + j];
    out[idx] = acc;
}

// ---------------------------------------------------------------------------
extern "C" void kernel_launch(void* const* d_in, const int* in_sizes, int n_in,
                              void* d_out, int out_size, void* d_ws, size_t ws_size,
                              hipStream_t stream)
{
    (void)in_sizes; (void)n_in; (void)out_size; (void)ws_size;
    const float* features = (const float*)d_in[0];
    const float* Wq  = (const float*)d_in[1];
    const float* bq  = (const float*)d_in[2];
    const float* Wk  = (const float*)d_in[3];
    const float* bk  = (const float*)d_in[4];
    const float* Wv  = (const float*)d_in[5];
    const float* bv  = (const float*)d_in[6];
    const float* Wo  = (const float*)d_in[7];
    const float* bo  = (const float*)d_in[8];
    const float* g1  = (const float*)d_in[9];
    const float* b1  = (const float*)d_in[10];
    const float* Wi  = (const float*)d_in[11];
    const float* bi  = (const float*)d_in[12];
    const float* Wd  = (const float*)d_in[13];
    const float* bd  = (const float*)d_in[14];
    const float* g2  = (const float*)d_in[15];
    const float* b2  = (const float*)d_in[16];
    const float* rel = (const float*)d_in[17];
    const float* fcw = (const float*)d_in[18];
    const float* fcb = (const float*)d_in[19];
    float* out = (float*)d_out;

    char* ws = (char*)d_ws;
    float*    xbuf = (float*)(ws);                    // 8 MB
    _Float16* qh1  = (_Float16*)(ws + ( 8u << 20));   // 4 MB (aliases xh)
    _Float16* xh   = qh1;                             // layer-0 f16 features
    _Float16* kh1  = (_Float16*)(ws + (12u << 20));
    _Float16* vt1  = (_Float16*)(ws + (16u << 20));
    _Float16* qh0  = (_Float16*)(ws + (20u << 20));
    _Float16* kh0  = (_Float16*)(ws + (24u << 20));
    _Float16* vt0  = (_Float16*)(ws + (28u << 20));
    _Float16* relh = (_Float16*)(ws + (32u << 20));            // 262 KB
    _Float16* wt   = (_Float16*)(ws + (32u << 20) + (512u << 10)); // 160 KB

    prep_kernel<<<2048, 256, 0, stream>>>(features, rel, Wq, Wk, Wv, Wo, Wi, Wd,
                                          xh, relh, wt);
    qkv_kernel<<<512, 256, 0, stream>>>(xh,
        wt, wt + 16384, wt + 32768, bq, bk, bv, qh0, kh0, vt0);

    for (int i = 0; i < 4; ++i) {
        const float* resid = (i == 0) ? features : xbuf;
        const int ni = (i < 3) ? (i + 1) : 3;
        const _Float16* qin = (i & 1) ? qh1 : qh0;
        const _Float16* kin = (i & 1) ? kh1 : kh0;
        const _Float16* vin = (i & 1) ? vt1 : vt0;
        _Float16* qout = (i & 1) ? qh0 : qh1;
        _Float16* kout = (i & 1) ? kh0 : kh1;
        _Float16* vout = (i & 1) ? vt0 : vt1;

        layer_kernel<<<512, 256, 0, stream>>>(qin, kin, vin,
            relh + i * 2047 * 16, resid,
            wt + 49152 + i * 4096, bo + i * 64, g1 + i * 64, b1 + i * 64,
            wt + 65536 + i * 2048, bi + i * 32,
            wt + 73728 + i * 2048, bd + i * 64, g2 + i * 64, b2 + i * 64,
            xbuf,
            (i < 3) ? 1 : 0,
            wt + ni * 4096, wt + 16384 + ni * 4096, wt + 32768 + ni * 4096,
            bq + ni * 64, bk + ni * 64, bv + ni * 64,
            qout, kout, vout);
    }
    final_kernel<<<768, 256, 0, stream>>>(xbuf, fcw, fcb, out);
}